// Round 5
// baseline (2283.570 us; speedup 1.0000x reference)
//
#include <hip/hip_runtime.h>
#include <math.h>

#define D_MODEL 1024
#define N_HEADS 16
#define HEAD_DIM 64
#define D_FF 4096
#define SEQ 2048
#define BATCH 2
#define M_ROWS (BATCH * SEQ)   // 4096

// ---------------------------------------------------------------------------
// LayerNorm over last dim (1024). One block per row, 256 threads, float4.
// ---------------------------------------------------------------------------
__global__ __launch_bounds__(256) void ln_kernel(const float* __restrict__ x,
                                                 const float* __restrict__ g,
                                                 const float* __restrict__ b,
                                                 float* __restrict__ o) {
    __shared__ float red[8];
    const int row = blockIdx.x;
    const int t = threadIdx.x;
    const float4 v = ((const float4*)(x + (size_t)row * D_MODEL))[t];

    float s = v.x + v.y + v.z + v.w;
    #pragma unroll
    for (int off = 32; off > 0; off >>= 1) s += __shfl_down(s, off, 64);
    const int wave = t >> 6, lane = t & 63;
    if (lane == 0) red[wave] = s;
    __syncthreads();
    const float mean = (red[0] + red[1] + red[2] + red[3]) * (1.0f / D_MODEL);

    const float dx = v.x - mean, dy = v.y - mean, dz = v.z - mean, dw = v.w - mean;
    float q = dx * dx + dy * dy + dz * dz + dw * dw;
    #pragma unroll
    for (int off = 32; off > 0; off >>= 1) q += __shfl_down(q, off, 64);
    if (lane == 0) red[4 + wave] = q;
    __syncthreads();
    const float var = (red[4] + red[5] + red[6] + red[7]) * (1.0f / D_MODEL);
    const float rstd = rsqrtf(var + 1e-5f);

    const float4 gv = ((const float4*)g)[t];
    const float4 bv = ((const float4*)b)[t];
    float4 ov;
    ov.x = dx * rstd * gv.x + bv.x;
    ov.y = dy * rstd * gv.y + bv.y;
    ov.z = dz * rstd * gv.z + bv.z;
    ov.w = dw * rstd * gv.w + bv.w;
    ((float4*)(o + (size_t)row * D_MODEL))[t] = ov;
}

// ---------------------------------------------------------------------------
// C[M,N] = A[M,K] @ W[N,K]^T + bias[N]   (optionally GELU, optionally +res)
// 128xTN tile (TN = 128 or 64), BK=16, 256 threads, 8x(TN/16) per thread.
// LDS is K-major (As[kk][row]); software-pipelined: next K-step's global
// loads issue right after the barrier so latency hides under compute.
// Known (accepted) inefficiency: W-side ds_read_b128 is 4-way bank-conflicted
// (tx*8 mod 32 repeats every 4 lanes) -> LDS-throughput-bound; the fix is the
// planned MFMA rewrite, not an fp32 swizzle (constant XOR can't despread it).
// ---------------------------------------------------------------------------
template <int GELU, int TN>
__global__ __launch_bounds__(256) void gemm_kernel(const float* __restrict__ A,
                                                   const float* __restrict__ W,
                                                   const float* __restrict__ bias,
                                                   const float* __restrict__ res,
                                                   float* __restrict__ C,
                                                   int M, int N, int K) {
    constexpr int JN = TN / 16;                 // per-thread N-cols: 8 or 4
    __shared__ float As[16][136];
    __shared__ float Ws[16][TN + 8];
    const int t = threadIdx.x;
    const int tx = t & 15, ty = t >> 4;         // 16x16 thread grid
    const int m0 = blockIdx.y * 128, n0 = blockIdx.x * TN;
    const int lrA = t >> 1, lkA = (t & 1) * 8;  // A staging: 2 thr/row, 8 floats
    const int lrW = (TN == 128) ? (t >> 1) : (t >> 2);
    const int lkW = (TN == 128) ? ((t & 1) * 8) : ((t & 3) * 4);
    const float* Ap = A + (size_t)(m0 + lrA) * K + lkA;
    const float* Wp = W + (size_t)(n0 + lrW) * K + lkW;

    // Prologue: prefetch first K-step into registers.
    float4 a0 = *(const float4*)(Ap);
    float4 a1 = *(const float4*)(Ap + 4);
    float4 w0 = *(const float4*)(Wp);
    float4 w1;
    if constexpr (TN == 128) w1 = *(const float4*)(Wp + 4);

    float acc[8][JN] = {};
    for (int k0 = 0; k0 < K; k0 += 16) {
        __syncthreads();          // previous iteration done reading LDS
        As[lkA + 0][lrA] = a0.x; As[lkA + 1][lrA] = a0.y;
        As[lkA + 2][lrA] = a0.z; As[lkA + 3][lrA] = a0.w;
        As[lkA + 4][lrA] = a1.x; As[lkA + 5][lrA] = a1.y;
        As[lkA + 6][lrA] = a1.z; As[lkA + 7][lrA] = a1.w;
        Ws[lkW + 0][lrW] = w0.x; Ws[lkW + 1][lrW] = w0.y;
        Ws[lkW + 2][lrW] = w0.z; Ws[lkW + 3][lrW] = w0.w;
        if constexpr (TN == 128) {
            Ws[lkW + 4][lrW] = w1.x; Ws[lkW + 5][lrW] = w1.y;
            Ws[lkW + 6][lrW] = w1.z; Ws[lkW + 7][lrW] = w1.w;
        }
        __syncthreads();          // tile visible
        if (k0 + 16 < K) {        // issue next-step loads; hide under compute
            a0 = *(const float4*)(Ap + k0 + 16);
            a1 = *(const float4*)(Ap + k0 + 20);
            w0 = *(const float4*)(Wp + k0 + 16);
            if constexpr (TN == 128) w1 = *(const float4*)(Wp + k0 + 20);
        }
        #pragma unroll
        for (int kk = 0; kk < 16; ++kk) {
            float ar[8], wr[JN];
            *(float4*)&ar[0] = *(const float4*)&As[kk][ty * 8];
            *(float4*)&ar[4] = *(const float4*)&As[kk][ty * 8 + 4];
            #pragma unroll
            for (int j4 = 0; j4 < JN; j4 += 4)
                *(float4*)&wr[j4] = *(const float4*)&Ws[kk][tx * JN + j4];
            #pragma unroll
            for (int i = 0; i < 8; ++i)
                #pragma unroll
                for (int j = 0; j < JN; ++j)
                    acc[i][j] = fmaf(ar[i], wr[j], acc[i][j]);
        }
    }

    float br[JN];
    #pragma unroll
    for (int j4 = 0; j4 < JN; j4 += 4)
        *(float4*)&br[j4] = *(const float4*)(bias + n0 + tx * JN + j4);
    #pragma unroll
    for (int i = 0; i < 8; ++i) {
        const int m = m0 + ty * 8 + i;
        float* cp = C + (size_t)m * N + n0 + tx * JN;
        float out[JN];
        #pragma unroll
        for (int j = 0; j < JN; ++j) {
            float v = acc[i][j] + br[j];
            if (GELU) v = 0.5f * v * (1.0f + erff(v * 0.70710678118654752f));
            out[j] = v;
        }
        if (res) {
            const float* rp = res + (size_t)m * N + n0 + tx * JN;
            #pragma unroll
            for (int j4 = 0; j4 < JN; j4 += 4) {
                const float4 r4 = *(const float4*)(rp + j4);
                out[j4 + 0] += r4.x; out[j4 + 1] += r4.y;
                out[j4 + 2] += r4.z; out[j4 + 3] += r4.w;
            }
        }
        #pragma unroll
        for (int j4 = 0; j4 < JN; j4 += 4) {
            float4 o4 = {out[j4], out[j4 + 1], out[j4 + 2], out[j4 + 3]};
            *(float4*)(cp + j4) = o4;
        }
    }
}

// ---------------------------------------------------------------------------
// Flash attention (fp32). One block per (q-tile of 64, head, batch).
// qkv rows: [3*d] = [which*1024 + h*64 + j]. ctx: [B,S,d] with d = h*64+j.
// Online softmax; Q,K transposed in LDS, V,P row-major in LDS.
// Q pre-scaled by 0.125 at load. K/V staging is software-pipelined: next
// tile's global loads issue before QK^T so HBM/L2 latency hides under it.
// ---------------------------------------------------------------------------
__global__ __launch_bounds__(256) void attn_kernel(const float* __restrict__ qkv,
                                                   const float* __restrict__ bias,
                                                   float* __restrict__ ctx) {
    __shared__ float Qt[64][68];
    __shared__ float Kt[64][68];
    __shared__ float Vs[64][68];
    __shared__ float Pt[64][68];
    const int qt = blockIdx.x, h = blockIdx.y, bb = blockIdx.z;
    const int t = threadIdx.x;
    const int tx = t & 15, ty = t >> 4;
    const int q0 = ty << 2, t0 = tx << 2;
    const size_t rowbase = (size_t)bb * SEQ;
    const int colQ = h * HEAD_DIM;
    const int srow = t >> 4, sc4 = (t & 15) << 2;   // staging row/col per thread

    // Load Q tile (64 x 64), pre-scaled, store transposed: Qt[j][row]
    #pragma unroll
    for (int i = 0; i < 4; ++i) {
        const int row = srow + i * 16;
        const float4 v = *(const float4*)(qkv + (rowbase + qt * 64 + row) * 3072 + colQ + sc4);
        Qt[sc4 + 0][row] = v.x * 0.125f; Qt[sc4 + 1][row] = v.y * 0.125f;
        Qt[sc4 + 2][row] = v.z * 0.125f; Qt[sc4 + 3][row] = v.w * 0.125f;
    }

    // Prologue: prefetch K/V tile 0 into registers (8 float4 = 32 VGPR).
    float4 kreg[4], vreg[4];
    #pragma unroll
    for (int i = 0; i < 4; ++i) {
        const int row = srow + i * 16;
        const size_t gr = (rowbase + row) * 3072 + colQ + sc4;
        kreg[i] = *(const float4*)(qkv + gr + 1024);
        vreg[i] = *(const float4*)(qkv + gr + 2048);
    }

    float Mr[4], Lr[4] = {0.f, 0.f, 0.f, 0.f};
    float O[4][4] = {};
    #pragma unroll
    for (int r = 0; r < 4; ++r) Mr[r] = -INFINITY;

    const float* biasp = bias + ((size_t)h * SEQ + qt * 64) * SEQ;

    for (int kt = 0; kt < SEQ / 64; ++kt) {
        __syncthreads();   // prior-iteration PV reads of Kt/Vs/Pt are done
        #pragma unroll
        for (int i = 0; i < 4; ++i) {
            const int row = srow + i * 16;
            Kt[sc4 + 0][row] = kreg[i].x; Kt[sc4 + 1][row] = kreg[i].y;
            Kt[sc4 + 2][row] = kreg[i].z; Kt[sc4 + 3][row] = kreg[i].w;
            *(float4*)&Vs[row][sc4] = vreg[i];
        }
        __syncthreads();
        if (kt + 1 < SEQ / 64) {   // issue next K/V loads; hide under QK^T+softmax
            #pragma unroll
            for (int i = 0; i < 4; ++i) {
                const int row = srow + i * 16;
                const size_t gr = (rowbase + (kt + 1) * 64 + row) * 3072 + colQ + sc4;
                kreg[i] = *(const float4*)(qkv + gr + 1024);
                vreg[i] = *(const float4*)(qkv + gr + 2048);
            }
        }

        // S tile: s[i][j] = Qscaled[q0+i] . K[t0+j] + bias
        float s[4][4] = {};
        #pragma unroll
        for (int kk = 0; kk < 64; ++kk) {
            const float4 a = *(const float4*)&Qt[kk][q0];
            const float4 k4 = *(const float4*)&Kt[kk][t0];
            const float ar[4] = {a.x, a.y, a.z, a.w};
            const float kr[4] = {k4.x, k4.y, k4.z, k4.w};
            #pragma unroll
            for (int i = 0; i < 4; ++i)
                #pragma unroll
                for (int j = 0; j < 4; ++j)
                    s[i][j] = fmaf(ar[i], kr[j], s[i][j]);
        }
        #pragma unroll
        for (int r = 0; r < 4; ++r) {
            const float4 bv = *(const float4*)(biasp + (size_t)(q0 + r) * SEQ + kt * 64 + t0);
            s[r][0] += bv.x;
            s[r][1] += bv.y;
            s[r][2] += bv.z;
            s[r][3] += bv.w;
        }
        // online softmax (row groups = 16 consecutive lanes)
        float corr[4];
        #pragma unroll
        for (int r = 0; r < 4; ++r) {
            float mx = fmaxf(fmaxf(s[r][0], s[r][1]), fmaxf(s[r][2], s[r][3]));
            #pragma unroll
            for (int off = 1; off < 16; off <<= 1) mx = fmaxf(mx, __shfl_xor(mx, off, 64));
            const float nm = fmaxf(Mr[r], mx);
            corr[r] = expf(Mr[r] - nm);
            Mr[r] = nm;
        }
        #pragma unroll
        for (int r = 0; r < 4; ++r) {
            const float p0 = expf(s[r][0] - Mr[r]);
            const float p1 = expf(s[r][1] - Mr[r]);
            const float p2 = expf(s[r][2] - Mr[r]);
            const float p3 = expf(s[r][3] - Mr[r]);
            Pt[t0 + 0][q0 + r] = p0; Pt[t0 + 1][q0 + r] = p1;
            Pt[t0 + 2][q0 + r] = p2; Pt[t0 + 3][q0 + r] = p3;
            float sum = p0 + p1 + p2 + p3;
            #pragma unroll
            for (int off = 1; off < 16; off <<= 1) sum += __shfl_xor(sum, off, 64);
            Lr[r] = Lr[r] * corr[r] + sum;
            O[r][0] *= corr[r]; O[r][1] *= corr[r];
            O[r][2] *= corr[r]; O[r][3] *= corr[r];
        }
        __syncthreads();   // Pt visible to all
        // O += P @ V   (cols j0 = t0)
        #pragma unroll
        for (int tt = 0; tt < 64; ++tt) {
            const float4 p4 = *(const float4*)&Pt[tt][q0];
            const float4 v4 = *(const float4*)&Vs[tt][t0];
            const float pr[4] = {p4.x, p4.y, p4.z, p4.w};
            const float vr[4] = {v4.x, v4.y, v4.z, v4.w};
            #pragma unroll
            for (int i = 0; i < 4; ++i)
                #pragma unroll
                for (int j = 0; j < 4; ++j)
                    O[i][j] = fmaf(pr[i], vr[j], O[i][j]);
        }
    }

    #pragma unroll
    for (int r = 0; r < 4; ++r) {
        const float inv = 1.0f / Lr[r];
        float4 ov = {O[r][0] * inv, O[r][1] * inv, O[r][2] * inv, O[r][3] * inv};
        *(float4*)(ctx + (rowbase + qt * 64 + q0 + r) * D_MODEL + colQ + t0) = ov;
    }
}

// ---------------------------------------------------------------------------
extern "C" void kernel_launch(void* const* d_in, const int* in_sizes, int n_in,
                              void* d_out, int out_size, void* d_ws, size_t ws_size,
                              hipStream_t stream) {
    const float* x          = (const float*)d_in[0];
    const float* attn_bias  = (const float*)d_in[1];
    const float* ln1_g      = (const float*)d_in[2];
    const float* ln1_b      = (const float*)d_in[3];
    const float* ln2_g      = (const float*)d_in[4];
    const float* ln2_b      = (const float*)d_in[5];
    const float* in_proj_w  = (const float*)d_in[6];
    const float* in_proj_b  = (const float*)d_in[7];
    const float* out_proj_w = (const float*)d_in[8];
    const float* out_proj_b = (const float*)d_in[9];
    const float* ffn_w1     = (const float*)d_in[10];
    const float* ffn_b1     = (const float*)d_in[11];
    const float* ffn_w2     = (const float*)d_in[12];
    const float* ffn_b2     = (const float*)d_in[13];
    float* out = (float*)d_out;

    // Workspace: w0 = 4M floats (nx / ctx / nx2, reused), w1 = 16M floats (qkv then h)
    float* w0 = (float*)d_ws;
    float* w1 = w0 + (size_t)M_ROWS * D_MODEL;          // after 16 MB

    // 1. LN1
    ln_kernel<<<M_ROWS, 256, 0, stream>>>(x, ln1_g, ln1_b, w0);
    // 2. qkv = nx @ in_proj_w^T + b   [4096, 3072]  (768 blocks ~ 3/CU)
    gemm_kernel<0, 128><<<dim3(3 * D_MODEL / 128, M_ROWS / 128), 256, 0, stream>>>(
        w0, in_proj_w, in_proj_b, nullptr, w1, M_ROWS, 3 * D_MODEL, D_MODEL);
    // 3. attention -> ctx (reuses w0)
    attn_kernel<<<dim3(SEQ / 64, N_HEADS, BATCH), 256, 0, stream>>>(w1, attn_bias, w0);
    // 4. x1 = x + ctx @ out_proj_w^T + b   -> d_out   (TN=64: 512 blocks ~ 2/CU)
    gemm_kernel<0, 64><<<dim3(D_MODEL / 64, M_ROWS / 128), 256, 0, stream>>>(
        w0, out_proj_w, out_proj_b, x, out, M_ROWS, D_MODEL, D_MODEL);
    // 5. LN2 (reads x1 from d_out) -> w0
    ln_kernel<<<M_ROWS, 256, 0, stream>>>(out, ln2_g, ln2_b, w0);
    // 6. h = gelu(nx2 @ ffn_w1^T + b1)   [4096, 4096] -> w1   (1024 blocks ~ 4/CU)
    gemm_kernel<1, 128><<<dim3(D_FF / 128, M_ROWS / 128), 256, 0, stream>>>(
        w0, ffn_w1, ffn_b1, nullptr, w1, M_ROWS, D_FF, D_MODEL);
    // 7. out = x1 + h @ ffn_w2^T + b2   (in-place on d_out; TN=64: 512 blocks)
    gemm_kernel<0, 64><<<dim3(D_MODEL / 64, M_ROWS / 128), 256, 0, stream>>>(
        w1, ffn_w2, ffn_b2, out, out, M_ROWS, D_MODEL, D_FF);
}

// Round 6
// 1179.455 us; speedup vs baseline: 1.9361x; 1.9361x over previous
//
#include <hip/hip_runtime.h>
#include <math.h>

#define D_MODEL 1024
#define N_HEADS 16
#define HEAD_DIM 64
#define D_FF 4096
#define SEQ 2048
#define BATCH 2
#define M_ROWS (BATCH * SEQ)   // 4096

typedef short  short8_t __attribute__((ext_vector_type(8)));   // bf16x8 frag (4 VGPR)
typedef short  short4_t __attribute__((ext_vector_type(4)));   // bf16x4 (8B store)
typedef float  float4_t __attribute__((ext_vector_type(4)));   // MFMA acc frag

// RNE float->bf16 (finite inputs only)
static __device__ __forceinline__ short f2bf(float f) {
    unsigned int u = __builtin_bit_cast(unsigned int, f);
    u += 0x7fffu + ((u >> 16) & 1u);
    return (short)(u >> 16);
}

// ---------------------------------------------------------------------------
// Bulk fp32 -> bf16 cast (weights). n4 = n/4.
// ---------------------------------------------------------------------------
__global__ __launch_bounds__(256) void f2bf_kernel(const float4* __restrict__ in,
                                                   short4_t* __restrict__ out, int n4) {
    const int i = blockIdx.x * 256 + threadIdx.x;
    if (i < n4) {
        const float4 v = in[i];
        short4_t o = {f2bf(v.x), f2bf(v.y), f2bf(v.z), f2bf(v.w)};
        out[i] = o;
    }
}

// ---------------------------------------------------------------------------
// LayerNorm over last dim (1024) -> bf16 output. One block per row.
// ---------------------------------------------------------------------------
__global__ __launch_bounds__(256) void ln_kernel(const float* __restrict__ x,
                                                 const float* __restrict__ g,
                                                 const float* __restrict__ b,
                                                 short* __restrict__ o) {
    __shared__ float red[8];
    const int row = blockIdx.x;
    const int t = threadIdx.x;
    const float4 v = ((const float4*)(x + (size_t)row * D_MODEL))[t];

    float s = v.x + v.y + v.z + v.w;
    #pragma unroll
    for (int off = 32; off > 0; off >>= 1) s += __shfl_down(s, off, 64);
    const int wave = t >> 6, lane = t & 63;
    if (lane == 0) red[wave] = s;
    __syncthreads();
    const float mean = (red[0] + red[1] + red[2] + red[3]) * (1.0f / D_MODEL);

    const float dx = v.x - mean, dy = v.y - mean, dz = v.z - mean, dw = v.w - mean;
    float q = dx * dx + dy * dy + dz * dz + dw * dw;
    #pragma unroll
    for (int off = 32; off > 0; off >>= 1) q += __shfl_down(q, off, 64);
    if (lane == 0) red[4 + wave] = q;
    __syncthreads();
    const float var = (red[4] + red[5] + red[6] + red[7]) * (1.0f / D_MODEL);
    const float rstd = rsqrtf(var + 1e-5f);

    const float4 gv = ((const float4*)g)[t];
    const float4 bv = ((const float4*)b)[t];
    short4_t ov = {f2bf(dx * rstd * gv.x + bv.x), f2bf(dy * rstd * gv.y + bv.y),
                   f2bf(dz * rstd * gv.z + bv.z), f2bf(dw * rstd * gv.w + bv.w)};
    ((short4_t*)(o + (size_t)row * D_MODEL))[t] = ov;
}

// ---------------------------------------------------------------------------
// bf16 MFMA GEMM: C[M,N] = A[M,K](bf16) @ W[N,K](bf16)^T + bias (+GELU/+res)
// Tile: BM x 128, BK=64, 256 threads (4 waves).
//   BM=128: waves 2x2, each 64x64 (4x4 frags).  BM=64: waves 1x4, each 64x32.
// LDS row-major [row][64 bf16] with T2 XOR swizzle: 16B-slot ^= (row&7), so
// fragment ds_read_b128 (lanes = 16 rows x 4 k-groups) is slot-uniform.
// MFMA: f32_16x16x32_bf16; A-frag lane l: row=l&15, k=(l>>4)*8+b (contig 8);
// C/D: col=lane&15, row=(lane>>4)*4+reg (m89-verified mapping).
// ---------------------------------------------------------------------------
template <int GELU, int RES, int OUTBF, int BM>
__global__ __launch_bounds__(256) void gemm_bf16_kernel(
    const short* __restrict__ A, const short* __restrict__ W,
    const float* __restrict__ bias, const float* __restrict__ res,
    void* __restrict__ Cv, int M, int N, int K) {
    constexpr int CH_A = BM / 32;               // A 16B-chunks per thread (4|2)
    constexpr int NR   = (BM == 128) ? 4 : 2;   // per-wave N frags
    __shared__ short As[BM * 64];
    __shared__ short Ws[128 * 64];
    const int t = threadIdx.x;
    const int m0 = blockIdx.y * BM, n0 = blockIdx.x * 128;
    const int wid = t >> 6, lane = t & 63;
    const int wm = (BM == 128) ? (wid >> 1) * 64 : 0;
    const int wn = (BM == 128) ? (wid & 1) * 64 : wid * 32;
    const int fr = lane & 15, fg = lane >> 4;
    const short* Ag = A + (size_t)m0 * K;
    const short* Wg = W + (size_t)n0 * K;

    short8_t aS[CH_A], wS[4];
    auto LOADG = [&](int k0) {
        #pragma unroll
        for (int i = 0; i < CH_A; ++i) {
            const int chunk = i * 256 + t, r = chunk >> 3, c = chunk & 7;
            aS[i] = *(const short8_t*)(Ag + (size_t)r * K + k0 + c * 8);
        }
        #pragma unroll
        for (int i = 0; i < 4; ++i) {
            const int chunk = i * 256 + t, r = chunk >> 3, c = chunk & 7;
            wS[i] = *(const short8_t*)(Wg + (size_t)r * K + k0 + c * 8);
        }
    };
    LOADG(0);

    float4_t acc[4][NR];
    #pragma unroll
    for (int mi = 0; mi < 4; ++mi)
        #pragma unroll
        for (int ni = 0; ni < NR; ++ni)
            acc[mi][ni] = (float4_t){0.f, 0.f, 0.f, 0.f};

    for (int k0 = 0; k0 < K; k0 += 64) {
        __syncthreads();
        #pragma unroll
        for (int i = 0; i < CH_A; ++i) {
            const int chunk = i * 256 + t, r = chunk >> 3, c = chunk & 7;
            *(short8_t*)&As[r * 64 + ((c ^ (r & 7)) << 3)] = aS[i];
        }
        #pragma unroll
        for (int i = 0; i < 4; ++i) {
            const int chunk = i * 256 + t, r = chunk >> 3, c = chunk & 7;
            *(short8_t*)&Ws[r * 64 + ((c ^ (r & 7)) << 3)] = wS[i];
        }
        __syncthreads();
        if (k0 + 64 < K) LOADG(k0 + 64);    // prefetch next tile under compute
        #pragma unroll
        for (int kk = 0; kk < 2; ++kk) {
            const int so = (((kk << 2) + fg) ^ (fr & 7)) << 3;
            short8_t af[4], wf[NR];
            #pragma unroll
            for (int mi = 0; mi < 4; ++mi)
                af[mi] = *(const short8_t*)&As[(wm + mi * 16 + fr) * 64 + so];
            #pragma unroll
            for (int ni = 0; ni < NR; ++ni)
                wf[ni] = *(const short8_t*)&Ws[(wn + ni * 16 + fr) * 64 + so];
            #pragma unroll
            for (int mi = 0; mi < 4; ++mi)
                #pragma unroll
                for (int ni = 0; ni < NR; ++ni)
                    acc[mi][ni] = __builtin_amdgcn_mfma_f32_16x16x32_bf16(
                        af[mi], wf[ni], acc[mi][ni], 0, 0, 0);
        }
    }

    float bv[NR];
    #pragma unroll
    for (int ni = 0; ni < NR; ++ni) bv[ni] = bias[n0 + wn + ni * 16 + fr];
    float* Cf = (float*)Cv;
    short* Cb = (short*)Cv;
    #pragma unroll
    for (int mi = 0; mi < 4; ++mi) {
        #pragma unroll
        for (int rg = 0; rg < 4; ++rg) {
            const int m = m0 + wm + mi * 16 + fg * 4 + rg;
            const size_t rowoff = (size_t)m * N + n0 + wn + fr;
            #pragma unroll
            for (int ni = 0; ni < NR; ++ni) {
                float v = acc[mi][ni][rg] + bv[ni];
                if (GELU) v = 0.5f * v * (1.0f + erff(v * 0.70710678118654752f));
                const size_t idx = rowoff + ni * 16;
                if (RES) v += res[idx];
                if (OUTBF) Cb[idx] = f2bf(v);
                else       Cf[idx] = v;
            }
        }
    }
}

// ---------------------------------------------------------------------------
// Flash attention (fp32, unchanged structure; now stores ctx as bf16).
// qkv rows: [3*d]; one block per (q-tile 64, head, batch); online softmax.
// ---------------------------------------------------------------------------
__global__ __launch_bounds__(256) void attn_kernel(const float* __restrict__ qkv,
                                                   const float* __restrict__ bias,
                                                   short* __restrict__ ctx) {
    __shared__ float Qt[64][68];
    __shared__ float Kt[64][68];
    __shared__ float Vs[64][68];
    __shared__ float Pt[64][68];
    const int qt = blockIdx.x, h = blockIdx.y, bb = blockIdx.z;
    const int t = threadIdx.x;
    const int tx = t & 15, ty = t >> 4;
    const int q0 = ty << 2, t0 = tx << 2;
    const size_t rowbase = (size_t)bb * SEQ;
    const int colQ = h * HEAD_DIM;
    const int srow = t >> 4, sc4 = (t & 15) << 2;

    #pragma unroll
    for (int i = 0; i < 4; ++i) {
        const int row = srow + i * 16;
        const float4 v = *(const float4*)(qkv + (rowbase + qt * 64 + row) * 3072 + colQ + sc4);
        Qt[sc4 + 0][row] = v.x * 0.125f; Qt[sc4 + 1][row] = v.y * 0.125f;
        Qt[sc4 + 2][row] = v.z * 0.125f; Qt[sc4 + 3][row] = v.w * 0.125f;
    }

    float4 kreg[4], vreg[4];
    #pragma unroll
    for (int i = 0; i < 4; ++i) {
        const int row = srow + i * 16;
        const size_t gr = (rowbase + row) * 3072 + colQ + sc4;
        kreg[i] = *(const float4*)(qkv + gr + 1024);
        vreg[i] = *(const float4*)(qkv + gr + 2048);
    }

    float Mr[4], Lr[4] = {0.f, 0.f, 0.f, 0.f};
    float O[4][4] = {};
    #pragma unroll
    for (int r = 0; r < 4; ++r) Mr[r] = -INFINITY;

    const float* biasp = bias + ((size_t)h * SEQ + qt * 64) * SEQ;

    for (int kt = 0; kt < SEQ / 64; ++kt) {
        __syncthreads();
        #pragma unroll
        for (int i = 0; i < 4; ++i) {
            const int row = srow + i * 16;
            Kt[sc4 + 0][row] = kreg[i].x; Kt[sc4 + 1][row] = kreg[i].y;
            Kt[sc4 + 2][row] = kreg[i].z; Kt[sc4 + 3][row] = kreg[i].w;
            *(float4*)&Vs[row][sc4] = vreg[i];
        }
        __syncthreads();
        if (kt + 1 < SEQ / 64) {
            #pragma unroll
            for (int i = 0; i < 4; ++i) {
                const int row = srow + i * 16;
                const size_t gr = (rowbase + (kt + 1) * 64 + row) * 3072 + colQ + sc4;
                kreg[i] = *(const float4*)(qkv + gr + 1024);
                vreg[i] = *(const float4*)(qkv + gr + 2048);
            }
        }

        float s[4][4] = {};
        #pragma unroll
        for (int kk = 0; kk < 64; ++kk) {
            const float4 a = *(const float4*)&Qt[kk][q0];
            const float4 k4 = *(const float4*)&Kt[kk][t0];
            const float ar[4] = {a.x, a.y, a.z, a.w};
            const float kr[4] = {k4.x, k4.y, k4.z, k4.w};
            #pragma unroll
            for (int i = 0; i < 4; ++i)
                #pragma unroll
                for (int j = 0; j < 4; ++j)
                    s[i][j] = fmaf(ar[i], kr[j], s[i][j]);
        }
        #pragma unroll
        for (int r = 0; r < 4; ++r) {
            const float4 bv = *(const float4*)(biasp + (size_t)(q0 + r) * SEQ + kt * 64 + t0);
            s[r][0] += bv.x; s[r][1] += bv.y; s[r][2] += bv.z; s[r][3] += bv.w;
        }
        float corr[4];
        #pragma unroll
        for (int r = 0; r < 4; ++r) {
            float mx = fmaxf(fmaxf(s[r][0], s[r][1]), fmaxf(s[r][2], s[r][3]));
            #pragma unroll
            for (int off = 1; off < 16; off <<= 1) mx = fmaxf(mx, __shfl_xor(mx, off, 64));
            const float nm = fmaxf(Mr[r], mx);
            corr[r] = expf(Mr[r] - nm);
            Mr[r] = nm;
        }
        #pragma unroll
        for (int r = 0; r < 4; ++r) {
            const float p0 = expf(s[r][0] - Mr[r]);
            const float p1 = expf(s[r][1] - Mr[r]);
            const float p2 = expf(s[r][2] - Mr[r]);
            const float p3 = expf(s[r][3] - Mr[r]);
            Pt[t0 + 0][q0 + r] = p0; Pt[t0 + 1][q0 + r] = p1;
            Pt[t0 + 2][q0 + r] = p2; Pt[t0 + 3][q0 + r] = p3;
            float sum = p0 + p1 + p2 + p3;
            #pragma unroll
            for (int off = 1; off < 16; off <<= 1) sum += __shfl_xor(sum, off, 64);
            Lr[r] = Lr[r] * corr[r] + sum;
            O[r][0] *= corr[r]; O[r][1] *= corr[r];
            O[r][2] *= corr[r]; O[r][3] *= corr[r];
        }
        __syncthreads();
        #pragma unroll
        for (int tt = 0; tt < 64; ++tt) {
            const float4 p4 = *(const float4*)&Pt[tt][q0];
            const float4 v4 = *(const float4*)&Vs[tt][t0];
            const float pr[4] = {p4.x, p4.y, p4.z, p4.w};
            const float vr[4] = {v4.x, v4.y, v4.z, v4.w};
            #pragma unroll
            for (int i = 0; i < 4; ++i)
                #pragma unroll
                for (int j = 0; j < 4; ++j)
                    O[i][j] = fmaf(pr[i], vr[j], O[i][j]);
        }
    }

    #pragma unroll
    for (int r = 0; r < 4; ++r) {
        const float inv = 1.0f / Lr[r];
        short4_t ov = {f2bf(O[r][0] * inv), f2bf(O[r][1] * inv),
                       f2bf(O[r][2] * inv), f2bf(O[r][3] * inv)};
        *(short4_t*)(ctx + (rowbase + qt * 64 + q0 + r) * D_MODEL + colQ + t0) = ov;
    }
}

// ---------------------------------------------------------------------------
extern "C" void kernel_launch(void* const* d_in, const int* in_sizes, int n_in,
                              void* d_out, int out_size, void* d_ws, size_t ws_size,
                              hipStream_t stream) {
    const float* x          = (const float*)d_in[0];
    const float* attn_bias  = (const float*)d_in[1];
    const float* ln1_g      = (const float*)d_in[2];
    const float* ln1_b      = (const float*)d_in[3];
    const float* ln2_g      = (const float*)d_in[4];
    const float* ln2_b      = (const float*)d_in[5];
    const float* in_proj_w  = (const float*)d_in[6];
    const float* in_proj_b  = (const float*)d_in[7];
    const float* out_proj_w = (const float*)d_in[8];
    const float* out_proj_b = (const float*)d_in[9];
    const float* ffn_w1     = (const float*)d_in[10];
    const float* ffn_b1     = (const float*)d_in[11];
    const float* ffn_w2     = (const float*)d_in[12];
    const float* ffn_b2     = (const float*)d_in[13];
    float* out = (float*)d_out;

    // Workspace layout (72 MB total):
    //   [0,48M):   qkv f32 (steps 2-3); then wF1B [0,8M) + wF2B [8,16M) + h [16,48M)
    //   [48,56M):  nx / nx2 bf16
    //   [56,64M):  ctx bf16
    //   [64,70M):  in_proj_w bf16;  [70,72M): out_proj_w bf16
    char* base = (char*)d_ws;
    float* qkv_f32 = (float*)base;
    short* wF1B    = (short*)base;
    short* wF2B    = (short*)(base + 8u * 1024 * 1024);
    short* h_bf    = (short*)(base + 16u * 1024 * 1024);
    short* nx_bf   = (short*)(base + 48u * 1024 * 1024);
    short* ctx_bf  = (short*)(base + 56u * 1024 * 1024);
    short* wInB    = (short*)(base + 64u * 1024 * 1024);
    short* wOutB   = (short*)(base + 70u * 1024 * 1024);

    // Weight casts needed before attention (ffn weights cast later, into dead qkv space)
    f2bf_kernel<<<3072, 256, 0, stream>>>((const float4*)in_proj_w, (short4_t*)wInB, 786432);
    f2bf_kernel<<<1024, 256, 0, stream>>>((const float4*)out_proj_w, (short4_t*)wOutB, 262144);

    // 1. LN1 -> nx (bf16)
    ln_kernel<<<M_ROWS, 256, 0, stream>>>(x, ln1_g, ln1_b, nx_bf);
    // 2. qkv = nx @ in_proj_w^T + b   [4096,3072] f32
    gemm_bf16_kernel<0, 0, 0, 128><<<dim3(24, 32), 256, 0, stream>>>(
        nx_bf, wInB, in_proj_b, nullptr, qkv_f32, M_ROWS, 3 * D_MODEL, D_MODEL);
    // 3. attention -> ctx (bf16)
    attn_kernel<<<dim3(SEQ / 64, N_HEADS, BATCH), 256, 0, stream>>>(qkv_f32, attn_bias, ctx_bf);
    // FFN weight casts (qkv region is dead after attention; stream order serializes)
    f2bf_kernel<<<4096, 256, 0, stream>>>((const float4*)ffn_w1, (short4_t*)wF1B, 1048576);
    f2bf_kernel<<<4096, 256, 0, stream>>>((const float4*)ffn_w2, (short4_t*)wF2B, 1048576);
    // 4. x1 = x + ctx @ out_proj_w^T + b  -> d_out (f32)   [BM=64: 512 blocks]
    gemm_bf16_kernel<0, 1, 0, 64><<<dim3(8, 64), 256, 0, stream>>>(
        ctx_bf, wOutB, out_proj_b, x, out, M_ROWS, D_MODEL, D_MODEL);
    // 5. LN2 -> nx2 (bf16)
    ln_kernel<<<M_ROWS, 256, 0, stream>>>(out, ln2_g, ln2_b, nx_bf);
    // 6. h = gelu(nx2 @ ffn_w1^T + b1) -> bf16  [4096,4096]
    gemm_bf16_kernel<1, 0, 1, 128><<<dim3(32, 32), 256, 0, stream>>>(
        nx_bf, wF1B, ffn_b1, nullptr, h_bf, M_ROWS, D_FF, D_MODEL);
    // 7. out = x1 + h @ ffn_w2^T + b2  (in-place residual on d_out)
    gemm_bf16_kernel<0, 1, 0, 64><<<dim3(8, 64), 256, 0, stream>>>(
        h_bf, wF2B, ffn_b2, out, out, M_ROWS, D_MODEL, D_FF);
}